// Round 1
// 255.530 us; speedup vs baseline: 1.0484x; 1.0484x over previous
//
#include <hip/hip_runtime.h>

#define IPB 10        // items per block (250 of 256 lanes active)
#define NT 256
#define NQ 25
#define KVD 9
#define QSCALE 0.4808983469629878f      /* log2(e)/3 : folds 1/sqrt(9) and exp->exp2 */
#define MSCALE (-1.4426950408889634e9f) /* -1e9 * log2(e) */

// dot of 8 floats from LDS (two b128) against xv[0..7], seeded
__device__ __forceinline__ float dot8(const float* __restrict__ w,
                                      const float* __restrict__ xv, float acc) {
  float4 a = *(const float4*)(w);
  float4 b = *(const float4*)(w + 4);
  acc = fmaf(a.x, xv[0], acc);
  acc = fmaf(a.y, xv[1], acc);
  acc = fmaf(a.z, xv[2], acc);
  acc = fmaf(a.w, xv[3], acc);
  acc = fmaf(b.x, xv[4], acc);
  acc = fmaf(b.y, xv[5], acc);
  acc = fmaf(b.z, xv[6], acc);
  acc = fmaf(b.w, xv[7], acc);
  return acc;
}

// 9-dim projection: out[e] = bias[e] + sum_d W[e][d]*xv[d], W split as 8+1
__device__ __forceinline__ void proj9(const float* __restrict__ w8,
                                      const float* __restrict__ w9,
                                      const float* __restrict__ bias,
                                      const float* __restrict__ xv,
                                      float* __restrict__ outv) {
  float4 na = *(const float4*)(w9);
  float4 nb = *(const float4*)(w9 + 4);
  float  nc = w9[8];
  float4 ba = *(const float4*)(bias);
  float4 bb = *(const float4*)(bias + 4);
  float  bc = bias[8];
  const float w9e[9]  = {na.x, na.y, na.z, na.w, nb.x, nb.y, nb.z, nb.w, nc};
  const float seed[9] = {ba.x, ba.y, ba.z, ba.w, bb.x, bb.y, bb.z, bb.w, bc};
#pragma unroll
  for (int e = 0; e < KVD; ++e)
    outv[e] = dot8(w8 + e * 8, xv, fmaf(w9e[e], xv[8], seed[e]));
}

// launch_bounds(NT, 6): LDS already caps occupancy at 6 blocks/CU = 6 waves/SIMD,
// so grant the allocator the matching ~84-VGPR budget. The previous build chose
// 40 VGPRs for an unreachable occupancy target and paid AGPR-spill VALU traffic
// (live set s[25]+o[9]+xv[9]+bases ~60 > 40, yet zero scratch bytes).
__global__ __launch_bounds__(NT, 6) void attn_fused(
    const float* __restrict__ x, const float* __restrict__ mask,
    const float* __restrict__ Wq, const float* __restrict__ bq,
    const float* __restrict__ Wk, const float* __restrict__ bk,
    const float* __restrict__ Wv, const float* __restrict__ bv,
    const float* __restrict__ gamma, const float* __restrict__ beta,
    float* __restrict__ out, int B) {
  // weights split: 8-float rows (b128-friendly) + packed 9th column
  __shared__ __align__(16) float sW8[3][4][KVD][8];   // 3456 B
  __shared__ __align__(16) float sW9[3][4][12];       //  576 B
  __shared__ __align__(16) float sBias[3][4][12];     //  576 B
  __shared__ __align__(16) float sK8[IPB][NQ][8];     // 8000 B
  __shared__ __align__(16) float sK9[IPB][28];        // 1120 B
  __shared__ __align__(16) float sV8[IPB][NQ][8];     // 8000 B
  __shared__ __align__(16) float sV9[IPB][28];        // 1120 B
  // total ~22.3 KB; mask/gamma/beta now come in as wave-uniform s_loads

  const int tid = threadIdx.x;
  const int il = tid / NQ;
  const int tk = tid - il * NQ;
  const long item = (long)blockIdx.x * IPB + il;
  const bool active = (tid < IPB * NQ) && (item < (long)B);

  // ---- prefetch x before staging: HBM latency hides behind weight staging ----
  float xv[KVD];
  if (active) {
    const float* xp = x + item * 225 + tk * KVD;
#pragma unroll
    for (int d = 0; d < KVD; ++d) xv[d] = xp[d];
  }

  // ---- stage parameters (q pre-scaled by log2e/3) ----
  for (int i = tid; i < 324; i += NT) {  // 4*9*9
    int g = i / 81;
    int r = i - g * 81;
    int e = r / 9;
    int d = r - e * 9;
    float a = Wq[i] * QSCALE, b = Wk[i], c = Wv[i];
    if (d < 8) {
      sW8[0][g][e][d] = a; sW8[1][g][e][d] = b; sW8[2][g][e][d] = c;
    } else {
      sW9[0][g][e] = a; sW9[1][g][e] = b; sW9[2][g][e] = c;
    }
  }
  for (int i = tid; i < 36; i += NT) {
    int g = i / 9, d = i - g * 9;
    sBias[0][g][d] = bq[i] * QSCALE;
    sBias[1][g][d] = bk[i];
    sBias[2][g][d] = bv[i];
  }
  __syncthreads();

  const int g = (tk < 3) ? 0 : (tk < 13) ? 1 : (tk < 23) ? 2 : 3;
  if (active) {
    // k and v share one temp array; q is computed after the barrier so its
    // registers don't sit live across the K/V store phase.
    float t[KVD];
    proj9(&sW8[1][g][0][0], &sW9[1][g][0], &sBias[1][g][0], xv, t);
    *(float4*)&sK8[il][tk][0] = make_float4(t[0], t[1], t[2], t[3]);
    *(float4*)&sK8[il][tk][4] = make_float4(t[4], t[5], t[6], t[7]);
    sK9[il][tk] = t[8];
    proj9(&sW8[2][g][0][0], &sW9[2][g][0], &sBias[2][g][0], xv, t);
    *(float4*)&sV8[il][tk][0] = make_float4(t[0], t[1], t[2], t[3]);
    *(float4*)&sV8[il][tk][4] = make_float4(t[4], t[5], t[6], t[7]);
    sV9[il][tk] = t[8];
  }
  __syncthreads();

  if (active) {
    float q[KVD];
    proj9(&sW8[0][g][0][0], &sW9[0][g][0], &sBias[0][g][0], xv, q);

    const float* kb = &sK8[il][0][0];
    const float* k9 = &sK9[il][0];
    const float* vb = &sV8[il][0][0];
    const float* v9 = &sV9[il][0];

    // seed scores with mask: mask[j] is wave-uniform -> s_load, one v_mul each
    float s[NQ];
#pragma unroll
    for (int j = 0; j < NQ; ++j) s[j] = mask[j] * MSCALE;

#pragma unroll
    for (int j = 0; j < NQ; ++j) s[j] = dot8(kb + j * 8, q, s[j]);
    const float q8 = q[8];
#pragma unroll
    for (int c = 0; c < 6; ++c) {
      float4 kc = *(const float4*)(k9 + 4 * c);
      s[4*c+0] = fmaf(q8, kc.x, s[4*c+0]);
      s[4*c+1] = fmaf(q8, kc.y, s[4*c+1]);
      s[4*c+2] = fmaf(q8, kc.z, s[4*c+2]);
      s[4*c+3] = fmaf(q8, kc.w, s[4*c+3]);
    }
    s[24] = fmaf(q8, k9[24], s[24]);

    // max: 4 parallel chains then combine (dep depth ~8 instead of 24)
    float m0 = s[0], m1 = s[1], m2 = s[2], m3 = s[3];
#pragma unroll
    for (int j = 4; j < 24; j += 4) {
      m0 = fmaxf(m0, s[j + 0]);
      m1 = fmaxf(m1, s[j + 1]);
      m2 = fmaxf(m2, s[j + 2]);
      m3 = fmaxf(m3, s[j + 3]);
    }
    const float m = fmaxf(fmaxf(fmaxf(m0, m1), fmaxf(m2, m3)), s[24]);

    // exp2 + 4-chain sum
    float u0 = 0.f, u1 = 0.f, u2 = 0.f, u3 = 0.f;
#pragma unroll
    for (int j = 0; j < 24; j += 4) {
      float p0 = __builtin_amdgcn_exp2f(s[j + 0] - m);
      float p1 = __builtin_amdgcn_exp2f(s[j + 1] - m);
      float p2 = __builtin_amdgcn_exp2f(s[j + 2] - m);
      float p3 = __builtin_amdgcn_exp2f(s[j + 3] - m);
      s[j + 0] = p0; s[j + 1] = p1; s[j + 2] = p2; s[j + 3] = p3;
      u0 += p0; u1 += p1; u2 += p2; u3 += p3;
    }
    float p24 = __builtin_amdgcn_exp2f(s[24] - m);
    s[24] = p24;
    const float sum = ((u0 + u1) + (u2 + u3)) + p24;
    const float inv = __builtin_amdgcn_rcpf(sum);

    float o[KVD];
#pragma unroll
    for (int d = 0; d < KVD; ++d) o[d] = 0.f;
#pragma unroll
    for (int j = 0; j < NQ; ++j) {
      float4 a = *(const float4*)(vb + j * 8);
      float4 b = *(const float4*)(vb + j * 8 + 4);
      const float p = s[j];
      o[0] = fmaf(p, a.x, o[0]);
      o[1] = fmaf(p, a.y, o[1]);
      o[2] = fmaf(p, a.z, o[2]);
      o[3] = fmaf(p, a.w, o[3]);
      o[4] = fmaf(p, b.x, o[4]);
      o[5] = fmaf(p, b.y, o[5]);
      o[6] = fmaf(p, b.z, o[6]);
      o[7] = fmaf(p, b.w, o[7]);
    }
#pragma unroll
    for (int c = 0; c < 6; ++c) {
      float4 vc = *(const float4*)(v9 + 4 * c);
      o[8] = fmaf(s[4*c+0], vc.x, o[8]);
      o[8] = fmaf(s[4*c+1], vc.y, o[8]);
      o[8] = fmaf(s[4*c+2], vc.z, o[8]);
      o[8] = fmaf(s[4*c+3], vc.w, o[8]);
    }
    o[8] = fmaf(s[24], v9[24], o[8]);

    // residual + one-pass LayerNorm
    float r[KVD];
    float sm = 0.f, sq = 0.f;
#pragma unroll
    for (int d = 0; d < KVD; ++d) {
      r[d] = fmaf(o[d], inv, xv[d]);
      sm += r[d];
      sq = fmaf(r[d], r[d], sq);
    }
    const float mu = sm * (1.0f / 9.0f);
    float var = fmaf(mu, -mu, sq * (1.0f / 9.0f));
    const float rs = __builtin_amdgcn_rsqf(var + 1e-5f);
    float* op = out + item * 225 + tk * KVD;
    // gamma/beta: wave-uniform s_loads, no LDS staging needed
#pragma unroll
    for (int d = 0; d < KVD; ++d)
      op[d] = fmaf((r[d] - mu) * rs, gamma[d], beta[d]);
  }
}

extern "C" void kernel_launch(void* const* d_in, const int* in_sizes, int n_in,
                              void* d_out, int out_size, void* d_ws, size_t ws_size,
                              hipStream_t stream) {
  const float* x     = (const float*)d_in[0];
  const float* mask  = (const float*)d_in[1];
  const float* Wq    = (const float*)d_in[2];
  const float* bq    = (const float*)d_in[3];
  const float* Wk    = (const float*)d_in[4];
  const float* bk    = (const float*)d_in[5];
  const float* Wv    = (const float*)d_in[6];
  const float* bv    = (const float*)d_in[7];
  const float* gamma = (const float*)d_in[8];
  const float* beta  = (const float*)d_in[9];
  float* out = (float*)d_out;
  const int B = in_sizes[0] / 225;
  const int grid = (B + IPB - 1) / IPB;
  attn_fused<<<grid, NT, 0, stream>>>(x, mask, Wq, bq, Wk, bk, Wv, bv,
                                      gamma, beta, out, B);
}